// Round 5
// baseline (174.177 us; speedup 1.0000x reference)
//
#include <hip/hip_runtime.h>

namespace {

typedef float v2f __attribute__((ext_vector_type(2)));

constexpr int NTAGS = 64;
constexpr int START_T = 62;
constexpr int STOP_T = 63;
constexpr int Bc = 512;
constexpr int Lc = 512;

template <int CTRL>
__device__ __forceinline__ float dpp_add(float x) {
  // x + quad_perm(x): pure-VALU cross-lane add within groups of 4 lanes.
  return x + __int_as_float(__builtin_amdgcn_update_dpp(
                 0, __float_as_int(x), CTRL, 0xf, 0xf, true));
}

__device__ __forceinline__ float wave_max(float v) {
#pragma unroll
  for (int off = 32; off >= 1; off >>= 1)
    v = fmaxf(v, __shfl_xor(v, off, 64));
  return v;
}

__device__ __forceinline__ float wave_sum(float v) {
#pragma unroll
  for (int off = 32; off >= 1; off >>= 1)
    v += __shfl_xor(v, off, 64);
  return v;
}

// One wave per batch. lane -> (lr = lane>>2, c = lane&3).
// Lane owns rows {lr+16k} (k=0..3) and j-chunk {16t+4c+r} (t,r=0..3).
// State v_i = exp(alpha_i - Msum*ln2) lives in registers: s_k = v[lr+16k],
// replicated across the 4 quad lanes (dpp reduction leaves all 4 equal).
// Redistribution for the next matvec is 16 ds_bpermute_b32 (reg->reg
// crossbar, no LDS store/load round trip): bp[t][r] = s_t of lane
// 4*(4c+r), fixed addresses precomputed in 4 VGPRs.
__global__ __launch_bounds__(64, 1) void crf_scan(
    const float* __restrict__ inputs,   // [B, L, 64]
    const int* __restrict__ tags,       // [B, L]
    const int* __restrict__ mask,       // [B, L]
    const float* __restrict__ trans,    // [64, 64]
    float* __restrict__ partial) {      // [B]
  __shared__ float fin[NTAGS];

  const int b = blockIdx.x;
  const int lane = threadIdx.x;
  const int lr = lane >> 2;
  const int c = lane & 3;

  // bpermute byte-addresses: source lane for (r) is 16c+4r -> addr 64c+16r.
  const int a0 = c * 64;
  const int a1 = c * 64 + 16;
  const int a2 = c * 64 + 32;
  const int a3 = c * 64 + 48;

  // E[k][p][r] = v2f{ exp(trans[m][16*(2p)+4c+r]), exp(trans[m][16*(2p+1)+4c+r]) }
  // with m = lr+16k.  8 v2f per row, 32 total (64 VGPRs).
#define DECLE(k) v2f E##k##_00, E##k##_01, E##k##_02, E##k##_03, \
                     E##k##_10, E##k##_11, E##k##_12, E##k##_13;
  DECLE(0) DECLE(1) DECLE(2) DECLE(3)
#define LOADE(k)                                                       \
  {                                                                    \
    const float* tp = trans + (lr + 16 * k) * NTAGS + 4 * c;           \
    E##k##_00 = (v2f){__expf(tp[0]), __expf(tp[16])};                  \
    E##k##_01 = (v2f){__expf(tp[1]), __expf(tp[17])};                  \
    E##k##_02 = (v2f){__expf(tp[2]), __expf(tp[18])};                  \
    E##k##_03 = (v2f){__expf(tp[3]), __expf(tp[19])};                  \
    E##k##_10 = (v2f){__expf(tp[32]), __expf(tp[48])};                 \
    E##k##_11 = (v2f){__expf(tp[33]), __expf(tp[49])};                 \
    E##k##_12 = (v2f){__expf(tp[34]), __expf(tp[50])};                 \
    E##k##_13 = (v2f){__expf(tp[35]), __expf(tp[51])};                 \
  }
  LOADE(0) LOADE(1) LOADE(2) LOADE(3)

  const float* emit_base = inputs + (size_t)b * Lc * NTAGS;
  const int* mask_b = mask + b * Lc;
  const int* tags_b = tags + b * Lc;

  int Msum = 0;
  // init: v one-hot at START_T=62 = 14 + 16*3 -> s3 = (lr==14)
  float s0 = 0.0f, s1 = 0.0f, s2 = 0.0f;
  float s3 = (lr == 14) ? 1.0f : 0.0f;

#define BP(dst, ar, st) \
  float dst = __int_as_float(__builtin_amdgcn_ds_bpermute((ar), __float_as_int(st)));

#define ROWF(k)                                                        \
    v2f ac##k##0 = E##k##_00 * bv00;                                   \
    v2f ac##k##1 = E##k##_10 * bv10;                                   \
    ac##k##0 += E##k##_01 * bv01;                                      \
    ac##k##1 += E##k##_11 * bv11;                                      \
    ac##k##0 += E##k##_02 * bv02;                                      \
    ac##k##1 += E##k##_12 * bv12;                                      \
    ac##k##0 += E##k##_03 * bv03;                                      \
    ac##k##1 += E##k##_13 * bv13;

#define STEP(W0, W1, W2, W3, MIDX)                                     \
  {                                                                    \
    /* rescale from stale exponent of v[0] (= s0 of lane 0) */         \
    const int sb = __builtin_amdgcn_readfirstlane(__float_as_int(s0)); \
    const unsigned e0 = ((unsigned)sb >> 23) & 0xffu;                  \
    const int d = (e0 == 0u) ? 0 : (int)e0 - 127;                      \
    Msum += d;                                                         \
    const float rs = __uint_as_float((unsigned)(127 - d) << 23);       \
    const int mv = __builtin_amdgcn_readlane(mrow, (MIDX));            \
    /* pull prev v: bp[t][r] = s_t of lane 16c+4r */                   \
    BP(b00, a0, s0) BP(b01, a1, s0) BP(b02, a2, s0) BP(b03, a3, s0)    \
    BP(b10, a0, s1) BP(b11, a1, s1) BP(b12, a2, s1) BP(b13, a3, s1)    \
    BP(b20, a0, s2) BP(b21, a1, s2) BP(b22, a2, s2) BP(b23, a3, s2)    \
    BP(b30, a0, s3) BP(b31, a1, s3) BP(b32, a2, s3) BP(b33, a3, s3)    \
    const float f0 = (W0) * rs, f1 = (W1) * rs;                        \
    const float f2 = (W2) * rs, f3 = (W3) * rs;                        \
    if (mv) {                                                          \
      v2f bv00 = {b00, b10}, bv01 = {b01, b11};                        \
      v2f bv02 = {b02, b12}, bv03 = {b03, b13};                        \
      v2f bv10 = {b20, b30}, bv11 = {b21, b31};                        \
      v2f bv12 = {b22, b32}, bv13 = {b23, b33};                        \
      ROWF(0) ROWF(1) ROWF(2) ROWF(3)                                  \
      v2f t0 = ac00 + ac01, t1 = ac10 + ac11;                          \
      v2f t2 = ac20 + ac21, t3 = ac30 + ac31;                          \
      float r0 = t0.x + t0.y, r1 = t1.x + t1.y;                        \
      float r2 = t2.x + t2.y, r3 = t3.x + t3.y;                        \
      r0 = dpp_add<0xB1>(r0); r1 = dpp_add<0xB1>(r1);                  \
      r2 = dpp_add<0xB1>(r2); r3 = dpp_add<0xB1>(r3);                  \
      r0 = dpp_add<0x4E>(r0); r1 = dpp_add<0x4E>(r1);                  \
      r2 = dpp_add<0x4E>(r2); r3 = dpp_add<0x4E>(r3);                  \
      s0 = r0 * f0; s1 = r1 * f1; s2 = r2 * f2; s3 = r3 * f3;          \
    } else {                                                           \
      /* mask==0: v'_i = sum_j v_j (no emit), all rows equal */        \
      float ss = ((b00 + b01) + (b02 + b03)) +                         \
                 ((b10 + b11) + (b12 + b13)) +                         \
                 ((b20 + b21) + (b22 + b23)) +                         \
                 ((b30 + b31) + (b32 + b33));                          \
      ss = dpp_add<0xB1>(ss); ss = dpp_add<0x4E>(ss);                  \
      ss *= rs;                                                        \
      s0 = s1 = s2 = s3 = ss;                                          \
    }                                                                  \
  }

  // w = exp(emit) prefetch: bank[q step][k row], 4 steps x 4 rows.
  float wA[4][4], wB[4][4];
#define PRE(Wb, ST)                                                    \
  {                                                                    \
    int s_ = (ST); s_ = s_ > (Lc - 4) ? (Lc - 4) : s_;                 \
    _Pragma("unroll") for (int q = 0; q < 4; ++q) {                    \
      const float* pp = emit_base + (size_t)(s_ + q) * NTAGS + lr;     \
      Wb[q][0] = __expf(pp[0]);                                        \
      Wb[q][1] = __expf(pp[16]);                                       \
      Wb[q][2] = __expf(pp[32]);                                       \
      Wb[q][3] = __expf(pp[48]);                                       \
    }                                                                  \
  }

  PRE(wA, 0)
  int mrow = mask_b[lane];

  for (int chunk = 0; chunk < 8; ++chunk) {
    const int cbase = chunk * 64;
    int mrow_nxt = mask_b[(chunk < 7 ? cbase + 64 : cbase) + lane];
    for (int gp = 0; gp < 8; ++gp) {
      const int base = cbase + gp * 8;
      const int mb = gp * 8;
      PRE(wB, base + 4)
      STEP(wA[0][0], wA[0][1], wA[0][2], wA[0][3], mb + 0)
      STEP(wA[1][0], wA[1][1], wA[1][2], wA[1][3], mb + 1)
      STEP(wA[2][0], wA[2][1], wA[2][2], wA[2][3], mb + 2)
      STEP(wA[3][0], wA[3][1], wA[3][2], wA[3][3], mb + 3)
      PRE(wA, base + 8)
      STEP(wB[0][0], wB[0][1], wB[0][2], wB[0][3], mb + 4)
      STEP(wB[1][0], wB[1][1], wB[1][2], wB[1][3], mb + 5)
      STEP(wB[2][0], wB[2][1], wB[2][2], wB[2][3], mb + 6)
      STEP(wB[3][0], wB[3][1], wB[3][2], wB[3][3], mb + 7)
    }
    mrow = mrow_nxt;
  }

  // ---- epilogue ----
  // stage final v to LDS (identity order), once.
  if (c == 0) {
    fin[lr] = s0;
    fin[lr + 16] = s1;
    fin[lr + 32] = s2;
    fin[lr + 48] = s3;
  }
  __syncthreads();

  // C = Msum * ln2 with exact hi/lo split (hi = 355/512, 9 mantissa bits).
  const float mf = (float)Msum;
  const float C = fmaf(mf, -2.1219444e-4f, mf * 0.693359375f);

  float alphav = __logf(fin[lane]) + C;
  float term = alphav + trans[STOP_T * NTAGS + lane];
  float mx = wave_max(term);
  float sden = wave_sum(__expf(term - mx));
  float logden = mx + __logf(sden);

  // numerator score: lanes parallel over timesteps (exact)
  float sc = 0.0f;
  for (int l = lane; l < Lc; l += 64) {
    int tl = tags_b[l];
    float mfl = (float)mask_b[l];
    if (l < Lc - 1) {
      int tn = tags_b[l + 1];
      float mfn = (float)mask_b[l + 1];
      sc += trans[tn * NTAGS + tl] * mfn +
            emit_base[(size_t)l * NTAGS + tl] * mfl;
    } else {
      sc += trans[STOP_T * NTAGS + tl] +
            emit_base[(size_t)l * NTAGS + tl] * mfl;
    }
  }
  if (lane == 0) sc += trans[tags_b[0] * NTAGS + START_T];
  float score = wave_sum(sc);

  if (lane == 0) partial[b] = score - logden;
}

__global__ void crf_reduce(const float* __restrict__ partial,
                           float* __restrict__ out) {
  const int lane = threadIdx.x;
  float s = 0.0f;
  for (int i = lane; i < Bc; i += 64) s += partial[i];
  s = wave_sum(s);
  if (lane == 0) out[0] = s;
}

}  // namespace

extern "C" void kernel_launch(void* const* d_in, const int* in_sizes, int n_in,
                              void* d_out, int out_size, void* d_ws,
                              size_t ws_size, hipStream_t stream) {
  const float* inputs = (const float*)d_in[0];
  const int* tags = (const int*)d_in[1];
  const int* mask = (const int*)d_in[2];
  const float* trans = (const float*)d_in[3];
  float* out = (float*)d_out;
  float* partial = (float*)d_ws;  // B floats of scratch

  crf_scan<<<Bc, 64, 0, stream>>>(inputs, tags, mask, trans, partial);
  crf_reduce<<<1, 64, 0, stream>>>(partial, out);
}